// Round 3
// baseline (522.689 us; speedup 1.0000x reference)
//
#include <hip/hip_runtime.h>

// Peeling propagation on bipartite graph. V=1e6, F=4.2e6, K=3 (edge e -> function e/3).
// T=5. Output: deg (V floats) in d_out.
//
// R11: frontier-driven rewrite. R9/R10 iteration path (~270us of 384) scanned all 4.2M
// functions x5 iters (12.6M random sgrp probes + ~7M random L2 svm probes per iter) for
// only ~50K total fired functions. Now:
//  * sort entries widened to u32 (vlocal:10|sign:1|flocal:12) in k_pack_sort.
//  * k_csr (new, per fine bin): gathers region spans, LDS counting-sort by vlocal,
//    emits var-major CSR (f<<1|sign) + row_off, AND subsumes k_accum (deg/sdeg accum,
//    packed/avm/svm init, initial frontier emit).
//  * k_fire: walks only frontier vars' CSR edges; atomicAnd on gpack bit63 dedups.
//  * k_update: clean-word early-exit; appends next frontier (wave-aggregated).

static constexpr int Vn = 1000000;
static constexpr int Fn = 4200000;
static constexpr int Tn = 5;

static constexpr int SBLK = 2048;                          // sort blocks / regions
static constexpr int FPB  = 2052;                          // functions/block (mult of 4)
static constexpr int BIN_BITS = 10;                        // fine bin = 1024 vars
static constexpr int BIN_SIZE = 1 << BIN_BITS;
static constexpr int NB  = (Vn + BIN_SIZE - 1) >> BIN_BITS;   // 977 fine bins
static constexpr int NBP = 1024;                           // padded fine-bin count (scan)
static constexpr int RCAP = 3 * FPB;                       // 6156 max entries/region
static constexpr int RSTRIDE = (RCAP + 63) & ~63;          // 6208 entries (u32 -> 24832B, 16B-aligned)
static constexpr int OROW = 1024;                          // offs row stride (u16)
static constexpr int AVW = 15680;                          // u64 mask words (padded >= 15632)
static constexpr int BCAP = 14336;                         // LDS staging cap per bin (avg 12.9K, +12 sigma)

// ---- fused pack + histogram + shuffle-scan + LDS-staged scatter + coalesced flush ----
__global__ __launch_bounds__(256) void k_pack_sort(
    const int* __restrict__ vidx, const float* __restrict__ ef,
    const float* __restrict__ afunc,
    unsigned long long* __restrict__ gpack,
    unsigned short* __restrict__ offs,      // [SBLK][OROW] exclusive fine-bin offsets
    unsigned int* __restrict__ sorted4)     // [SBLK][RSTRIDE] u32 entries
{
    __shared__ unsigned int hist[NBP];
    __shared__ unsigned int cur[NBP];
    __shared__ unsigned int wsum[4];
    __shared__ unsigned int s_total;
    __shared__ __align__(16) unsigned int st[RSTRIDE];   // 24.8 KB staged region

    const int k = blockIdx.x;
    const int f0 = k * FPB;
    int n = Fn - f0; if (n < 0) n = 0; if (n > FPB) n = FPB;
    const int n4 = n >> 2;

    for (int i = threadIdx.x; i < NBP; i += 256) hist[i] = 0u;
    __syncthreads();

    // pass 1 (4-wide): read vidx/ef/afunc once, emit gpack, histogram fine bins
    for (int j = threadIdx.x; j < n4; j += 256) {
        const int fb = f0 + 4 * j, e = 3 * fb;
        int4 va = *(const int4*)(vidx + e);
        int4 vb = *(const int4*)(vidx + e + 4);
        int4 vc = *(const int4*)(vidx + e + 8);
        float4 ea = *(const float4*)(ef + e);
        float4 eb = *(const float4*)(ef + e + 4);
        float4 ec = *(const float4*)(ef + e + 8);
        float4 a4 = *(const float4*)(afunc + fb);
        int      vv[12] = {va.x, va.y, va.z, va.w, vb.x, vb.y, vb.z, vb.w, vc.x, vc.y, vc.z, vc.w};
        float    ss[12] = {ea.x, ea.y, ea.z, ea.w, eb.x, eb.y, eb.z, eb.w, ec.x, ec.y, ec.z, ec.w};
        float    aa[4]  = {a4.x, a4.y, a4.z, a4.w};
        unsigned long long gq[4];
        #pragma unroll
        for (int q = 0; q < 4; ++q) {
            int v0 = vv[3 * q], v1 = vv[3 * q + 1], v2 = vv[3 * q + 2];
            unsigned int s0 = ss[3 * q]     > 0.0f ? 1u : 0u;
            unsigned int s1 = ss[3 * q + 1] > 0.0f ? 1u : 0u;
            unsigned int s2 = ss[3 * q + 2] > 0.0f ? 1u : 0u;
            unsigned int act = aa[q] != 0.0f ? 1u : 0u;
            gq[q] = (unsigned long long)(unsigned int)v0
                  | ((unsigned long long)(unsigned int)v1 << 20)
                  | ((unsigned long long)(unsigned int)v2 << 40)
                  | ((unsigned long long)s0 << 60)
                  | ((unsigned long long)s1 << 61)
                  | ((unsigned long long)s2 << 62)
                  | ((unsigned long long)act << 63);
            if (act) {
                atomicAdd(&hist[v0 >> BIN_BITS], 1u);
                atomicAdd(&hist[v1 >> BIN_BITS], 1u);
                atomicAdd(&hist[v2 >> BIN_BITS], 1u);
            }
        }
        *(ulonglong2*)(gpack + fb)     = make_ulonglong2(gq[0], gq[1]);
        *(ulonglong2*)(gpack + fb + 2) = make_ulonglong2(gq[2], gq[3]);
    }
    // scalar tail (0..3 functions)
    for (int i = 4 * n4 + threadIdx.x; i < n; i += 256) {
        const int f = f0 + i, e0 = 3 * f;
        int v0 = vidx[e0], v1 = vidx[e0 + 1], v2 = vidx[e0 + 2];
        unsigned int s0 = ef[e0]     > 0.0f ? 1u : 0u;
        unsigned int s1 = ef[e0 + 1] > 0.0f ? 1u : 0u;
        unsigned int s2 = ef[e0 + 2] > 0.0f ? 1u : 0u;
        unsigned int act = afunc[f] != 0.0f ? 1u : 0u;
        unsigned long long g = (unsigned long long)(unsigned int)v0
                             | ((unsigned long long)(unsigned int)v1 << 20)
                             | ((unsigned long long)(unsigned int)v2 << 40)
                             | ((unsigned long long)s0 << 60)
                             | ((unsigned long long)s1 << 61)
                             | ((unsigned long long)s2 << 62)
                             | ((unsigned long long)act << 63);
        gpack[f] = g;
        if (act) {
            atomicAdd(&hist[v0 >> BIN_BITS], 1u);
            atomicAdd(&hist[v1 >> BIN_BITS], 1u);
            atomicAdd(&hist[v2 >> BIN_BITS], 1u);
        }
    }
    __syncthreads();

    // shuffle-based exclusive scan over 1024 fine bins (256 threads x 4 bins)
    {
        const int t = threadIdx.x, lane = t & 63, wid = t >> 6;
        unsigned int a0 = hist[4 * t], a1 = hist[4 * t + 1];
        unsigned int a2 = hist[4 * t + 2], a3 = hist[4 * t + 3];
        unsigned int tsum = a0 + a1 + a2 + a3;
        unsigned int x = tsum;
        #pragma unroll
        for (int off = 1; off < 64; off <<= 1) {
            unsigned int y = (unsigned int)__shfl_up((int)x, off);
            if (lane >= off) x += y;
        }
        if (lane == 63) wsum[wid] = x;
        __syncthreads();
        unsigned int wbase = 0;
        for (int w = 0; w < wid; ++w) wbase += wsum[w];
        unsigned int e0x = wbase + x - tsum;      // exclusive prefix of bin 4t
        unsigned int e1x = e0x + a0, e2x = e1x + a1, e3x = e2x + a2;
        cur[4 * t] = e0x; cur[4 * t + 1] = e1x; cur[4 * t + 2] = e2x; cur[4 * t + 3] = e3x;
        if (t == 255) s_total = e3x + a3;         // inclusive total (= #active entries)
        unsigned short* row = offs + (size_t)k * OROW;
        if (4 * t     <= NB) row[4 * t]     = (unsigned short)e0x;
        if (4 * t + 1 <= NB) row[4 * t + 1] = (unsigned short)e1x;
        if (4 * t + 2 <= NB) row[4 * t + 2] = (unsigned short)e2x;
        if (4 * t + 3 <= NB) row[4 * t + 3] = (unsigned short)e3x;
    }
    __syncthreads();

    // pass 2 (4-wide): re-read gpack (cache-hot), scatter u32 entries into LDS region.
    // entry = vlocal:10 | sign:1<<10 | flocal:12<<11
    for (int j = threadIdx.x; j < n4; j += 256) {
        const int fb = f0 + 4 * j;
        ulonglong2 ga = *(const ulonglong2*)(gpack + fb);
        ulonglong2 gb = *(const ulonglong2*)(gpack + fb + 2);
        unsigned long long gq[4] = {ga.x, ga.y, gb.x, gb.y};
        #pragma unroll
        for (int q = 0; q < 4; ++q) {
            unsigned long long g = gq[q];
            if ((long long)g < 0) {
                unsigned int fl = (unsigned int)(4 * j + q) << 11;
                unsigned int v0 = (unsigned int)(g & 0xFFFFFu);
                unsigned int v1 = (unsigned int)((g >> 20) & 0xFFFFFu);
                unsigned int v2 = (unsigned int)((g >> 40) & 0xFFFFFu);
                unsigned int sl0 = atomicAdd(&cur[v0 >> BIN_BITS], 1u);
                st[sl0] = (v0 & (BIN_SIZE - 1)) | (((unsigned int)(g >> 60) & 1u) << 10) | fl;
                unsigned int sl1 = atomicAdd(&cur[v1 >> BIN_BITS], 1u);
                st[sl1] = (v1 & (BIN_SIZE - 1)) | (((unsigned int)(g >> 61) & 1u) << 10) | fl;
                unsigned int sl2 = atomicAdd(&cur[v2 >> BIN_BITS], 1u);
                st[sl2] = (v2 & (BIN_SIZE - 1)) | (((unsigned int)(g >> 62) & 1u) << 10) | fl;
            }
        }
    }
    for (int i = 4 * n4 + threadIdx.x; i < n; i += 256) {
        unsigned long long g = gpack[f0 + i];
        if ((long long)g < 0) {
            unsigned int fl = (unsigned int)i << 11;
            unsigned int v0 = (unsigned int)(g & 0xFFFFFu);
            unsigned int v1 = (unsigned int)((g >> 20) & 0xFFFFFu);
            unsigned int v2 = (unsigned int)((g >> 40) & 0xFFFFFu);
            unsigned int sl0 = atomicAdd(&cur[v0 >> BIN_BITS], 1u);
            st[sl0] = (v0 & (BIN_SIZE - 1)) | (((unsigned int)(g >> 60) & 1u) << 10) | fl;
            unsigned int sl1 = atomicAdd(&cur[v1 >> BIN_BITS], 1u);
            st[sl1] = (v1 & (BIN_SIZE - 1)) | (((unsigned int)(g >> 61) & 1u) << 10) | fl;
            unsigned int sl2 = atomicAdd(&cur[v2 >> BIN_BITS], 1u);
            st[sl2] = (v2 & (BIN_SIZE - 1)) | (((unsigned int)(g >> 62) & 1u) << 10) | fl;
        }
    }
    __syncthreads();

    // coalesced flush: LDS region -> global, 16B vectors
    {
        const int tot = (int)s_total;
        const int nvec = (tot + 3) >> 2;               // 4 u32 per int4
        int4* __restrict__ dst = (int4*)(sorted4 + (size_t)k * RSTRIDE);
        const int4* __restrict__ src = (const int4*)st;
        for (int i = threadIdx.x; i < nvec; i += 256) dst[i] = src[i];
    }
}

// ---- tiled transpose: offs [SBLK][1024] -> offs_T [1024][SBLK] ----
__global__ __launch_bounds__(256) void k_transpose(const unsigned short* __restrict__ in,
                                                   unsigned short* __restrict__ out) {
    __shared__ unsigned short t[64][65];
    const int bx = blockIdx.x;   // 16 col tiles (1024/64)
    const int by = blockIdx.y;   // 32 row tiles (2048/64)
    for (int i = threadIdx.x; i < 64 * 64; i += 256) {
        int r = i >> 6, c = i & 63;
        t[r][c] = in[(size_t)(by * 64 + r) * OROW + (bx * 64 + c)];
    }
    __syncthreads();
    for (int i = threadIdx.x; i < 64 * 64; i += 256) {
        int r = i >> 6, c = i & 63;
        out[(size_t)(bx * 64 + r) * SBLK + (by * 64 + c)] = t[c][r];
    }
}

// ---- per-bin totals: one wave per bin ----
__global__ __launch_bounds__(256) void k_bin_total(const unsigned short* __restrict__ offs_T,
                                                   unsigned int* __restrict__ bin_total)
{
    int b = blockIdx.x * 4 + (threadIdx.x >> 6);
    int lane = threadIdx.x & 63;
    if (b >= NB) return;
    const unsigned short* ra = offs_T + (size_t)b * SBLK;
    const unsigned short* rb = ra + SBLK;
    unsigned int s = 0;
    for (int k = lane; k < SBLK; k += 64)
        s += (unsigned int)rb[k] - (unsigned int)ra[k];
    #pragma unroll
    for (int off = 32; off > 0; off >>= 1) s += (unsigned int)__shfl_down((int)s, off);
    if (lane == 0) bin_total[b] = s;
}

// ---- exclusive scan over bins (single block); also zeroes frontier counters ----
__global__ __launch_bounds__(1024) void k_bin_scan(const unsigned int* __restrict__ bin_total,
                                                   unsigned int* __restrict__ bin_base,
                                                   unsigned int* __restrict__ cnts)
{
    __shared__ unsigned int wsum[16];
    const int tid = threadIdx.x, lane = tid & 63, w = tid >> 6;
    unsigned int val = (tid < NB) ? bin_total[tid] : 0u;
    unsigned int x = val;
    #pragma unroll
    for (int off = 1; off < 64; off <<= 1) {
        unsigned int y = (unsigned int)__shfl_up((int)x, off);
        if (lane >= off) x += y;
    }
    if (lane == 63) wsum[w] = x;
    __syncthreads();
    if (w == 0 && lane < 16) {
        unsigned int s = wsum[lane];
        #pragma unroll
        for (int off = 1; off < 16; off <<= 1) {
            unsigned int y = (unsigned int)__shfl_up((int)s, off);
            if (lane >= off) s += y;
        }
        wsum[lane] = s;
    }
    __syncthreads();
    unsigned int wbase = (w == 0) ? 0u : wsum[w - 1];
    unsigned int excl = wbase + x - val;
    if (tid < NB) bin_base[tid] = excl;
    if (tid == NB - 1) bin_base[NB] = excl + val;
    if (tid < 8) cnts[tid] = 0u;
}

// ---- per-bin CSR build + deg/sdeg init + masks + initial frontier ----
__global__ __launch_bounds__(1024) void k_csr(
    const unsigned short* __restrict__ offs_T,
    const unsigned int* __restrict__ sorted4,
    const unsigned int* __restrict__ bin_base,
    const float* __restrict__ avars,
    unsigned int* __restrict__ csr,
    unsigned int* __restrict__ row_off,
    unsigned int* __restrict__ packed,
    unsigned long long* __restrict__ avm,
    unsigned long long* __restrict__ svm,
    unsigned int* __restrict__ frontier0,
    unsigned int* __restrict__ cnt0)
{
    __shared__ unsigned short rA[SBLK], rB[SBLK];     // 8 KB
    __shared__ unsigned int acc[BIN_SIZE];            // 4 KB: cnt<<16 | pos
    __shared__ unsigned int cur[BIN_SIZE];            // 4 KB: prefix, then cursor
    __shared__ unsigned int lcl[BCAP];                // 56 KB staged CSR entries
    __shared__ unsigned int wsum[16];
    const int b = blockIdx.x;
    const int tid = threadIdx.x;
    const unsigned int bb = bin_base[b];
    acc[tid] = 0u;
    rA[tid]        = offs_T[(size_t)b * SBLK + tid];
    rA[tid + 1024] = offs_T[(size_t)b * SBLK + tid + 1024];
    rB[tid]        = offs_T[(size_t)(b + 1) * SBLK + tid];
    rB[tid + 1024] = offs_T[(size_t)(b + 1) * SBLK + tid + 1024];
    __syncthreads();
    // pass 1: per-var count + sign accum
    for (int k = tid; k < SBLK; k += 1024) {
        const unsigned int base = (unsigned int)k * RSTRIDE;
        const int s0 = rA[k], s1 = rB[k];
        for (int e = s0; e < s1; ++e) {
            unsigned int val = sorted4[base + e];
            atomicAdd(&acc[val & (BIN_SIZE - 1)], 0x10000u | ((val >> 10) & 1u));
        }
    }
    __syncthreads();
    // exclusive scan of per-var counts -> cur
    {
        unsigned int valc = acc[tid] >> 16;
        const int lane = tid & 63, w = tid >> 6;
        unsigned int x = valc;
        #pragma unroll
        for (int off = 1; off < 64; off <<= 1) {
            unsigned int y = (unsigned int)__shfl_up((int)x, off);
            if (lane >= off) x += y;
        }
        if (lane == 63) wsum[w] = x;
        __syncthreads();
        if (w == 0 && lane < 16) {
            unsigned int s = wsum[lane];
            #pragma unroll
            for (int off = 1; off < 16; off <<= 1) {
                unsigned int y = (unsigned int)__shfl_up((int)s, off);
                if (lane >= off) s += y;
            }
            wsum[lane] = s;
        }
        __syncthreads();
        unsigned int wbase = (w == 0) ? 0u : wsum[w - 1];
        cur[tid] = wbase + x - valc;
    }
    __syncthreads();
    // pass 2: scatter CSR entries into LDS staging (rare overflow -> direct global)
    for (int k = tid; k < SBLK; k += 1024) {
        const unsigned int base = (unsigned int)k * RSTRIDE;
        const unsigned int fbk = (unsigned int)k * FPB;
        const int s0 = rA[k], s1 = rB[k];
        for (int e = s0; e < s1; ++e) {
            unsigned int val = sorted4[base + e];
            unsigned int dst = atomicAdd(&cur[val & (BIN_SIZE - 1)], 1u);
            unsigned int ent = ((fbk + (val >> 11)) << 1) | ((val >> 10) & 1u);
            if (dst < BCAP) lcl[dst] = ent; else csr[bb + dst] = ent;
        }
    }
    __syncthreads();
    // coalesced flush
    {
        const int total = (int)cur[BIN_SIZE - 1];
        const int lim = total < BCAP ? total : BCAP;
        for (int i = tid; i < lim; i += 1024) csr[bb + i] = lcl[i];
    }
    // per-var outputs: row_off, packed, masks, initial frontier
    {
        const int vl = tid;
        const int v = (b << BIN_BITS) + vl;
        const unsigned int a = acc[vl];
        const unsigned int cntv = a >> 16, pos = a & 0xFFFFu;
        const unsigned int pref = cur[vl] - cntv;     // cursor final - count = prefix
        if (v <= Vn) row_off[v] = bb + pref;
        const bool valid = v < Vn;
        const bool av = valid && (avars[v] != 0.0f);
        const bool sv = av && (pos == 0u || pos == cntv);   // deg == |sdeg|
        unsigned long long avb = __ballot(av);
        unsigned long long svb = __ballot(sv);
        if (valid) packed[v] = a;
        const int lane = tid & 63;
        if (lane == 0 && valid) {
            avm[v >> 6] = avb;
            svm[v >> 6] = svb;
        }
        unsigned int nset = (unsigned int)__popcll(svb);
        unsigned int fb = 0;
        if (lane == 0 && nset) fb = atomicAdd(cnt0, nset);
        fb = (unsigned int)__shfl((int)fb, 0);
        if (sv) {
            unsigned int rank = (unsigned int)__popcll(svb & ((1ull << lane) - 1ull));
            frontier0[fb + rank] = (unsigned int)v;
        }
    }
}

__global__ void k_zero_tmp(unsigned int* __restrict__ tmp, unsigned char* __restrict__ tgrp) {
    int v = blockIdx.x * blockDim.x + threadIdx.x;
    if (v < Vn) tmp[v] = 0u;
    if (v < AVW) tgrp[v] = 0;
}

// ---- iteration: fire functions of frontier vars (O(fired), not O(F)) ----
__global__ void k_fire(const unsigned int* __restrict__ row_off,
                       const unsigned int* __restrict__ csr,
                       unsigned long long* __restrict__ gpack,
                       const unsigned int* __restrict__ frontier_in,
                       const unsigned int* __restrict__ cnt_in,
                       unsigned int* __restrict__ cnt_out,
                       unsigned int* __restrict__ tmp,
                       unsigned char* __restrict__ tgrp)
{
    const int gid = blockIdx.x * blockDim.x + threadIdx.x;
    if (gid == 0) *cnt_out = 0u;                    // prepare next frontier counter
    const int n = (int)*cnt_in;
    const int stride = gridDim.x * blockDim.x;
    for (int i = gid; i < n; i += stride) {
        const unsigned int v = frontier_in[i];
        const unsigned int lo = row_off[v], hi = row_off[v + 1];
        for (unsigned int j = lo; j < hi; ++j) {
            const unsigned int f = csr[j] >> 1;
            const unsigned long long old = atomicAnd(&gpack[f], ~(1ull << 63));
            if ((long long)old < 0) {               // we deactivated it: fire exactly once
                const unsigned int v0 = (unsigned int)(old & 0xFFFFFu);
                const unsigned int v1 = (unsigned int)((old >> 20) & 0xFFFFFu);
                const unsigned int v2 = (unsigned int)((old >> 40) & 0xFFFFFu);
                atomicAdd(&tmp[v0], 0x10000u | (unsigned int)((old >> 60) & 1u));
                atomicAdd(&tmp[v1], 0x10000u | (unsigned int)((old >> 61) & 1u));
                atomicAdd(&tmp[v2], 0x10000u | (unsigned int)((old >> 62) & 1u));
                tgrp[v0 >> 6] = 1; tgrp[v1 >> 6] = 1; tgrp[v2 >> 6] = 1;
            }
        }
    }
}

// ---- iteration: variable side. Clean-word early-exit; next-frontier append. ----
__global__ void k_update(unsigned int* __restrict__ packed,
                         unsigned int* __restrict__ tmp,
                         unsigned long long* __restrict__ avm,
                         unsigned long long* __restrict__ svm,
                         unsigned char* __restrict__ tgrp,
                         unsigned int* __restrict__ frontier_out,
                         unsigned int* __restrict__ cnt_out,
                         float* __restrict__ deg, int write_deg)
{
    const int v = blockIdx.x * blockDim.x + threadIdx.x;
    const int lane = threadIdx.x & 63;
    const bool valid = v < Vn;
    unsigned long long avw = 0ull, svw = 0ull;
    unsigned char tg = 0;
    if (valid) {
        avw = avm[v >> 6]; svw = svm[v >> 6];          // wave-broadcast loads
        tg = tgrp[v >> 6];
    }
    if (!write_deg && !tg && svw == 0ull) return;       // clean word: nothing changes
    const bool av_old = valid && ((avw >> lane) & 1ull);
    const bool sv     = valid && ((svw >> lane) & 1ull);
    const bool av_new = av_old && !sv;                  // av *= (1 - single_v)
    unsigned int p = 0u;
    if (valid) {
        p = packed[v];
        if (tg) {
            unsigned int tp = tmp[v];
            if (tp != 0u) {
                if (av_old) { p -= tp; packed[v] = p; } // deg -= seg*av (field-safe)
                tmp[v] = 0u;
            }
        }
    }
    const unsigned int c = p >> 16, pos = p & 0xFFFFu;
    const bool nsv = av_new && (pos == 0u || pos == c); // next single_v
    unsigned long long nsvb = __ballot(nsv);
    if (lane == 0 && valid) {
        svm[v >> 6] = nsvb;
        avm[v >> 6] = avw & ~svw;
        if (tg) tgrp[v >> 6] = 0;
    }
    unsigned int nset = (unsigned int)__popcll(nsvb);
    unsigned int base = 0;
    if (lane == 0 && nset) base = atomicAdd(cnt_out, nset);
    base = (unsigned int)__shfl((int)base, 0);
    if (nsv) {
        unsigned int rank = (unsigned int)__popcll(nsvb & ((1ull << lane) - 1ull));
        frontier_out[base + rank] = (unsigned int)v;
    }
    if (write_deg && valid) deg[v] = (float)c;
}

extern "C" void kernel_launch(void* const* d_in, const int* in_sizes, int n_in,
                              void* d_out, int out_size, void* d_ws, size_t ws_size,
                              hipStream_t stream) {
    const int*   graph_map        = (const int*)d_in[0];   // row0 = vidx
    const float* edge_feature     = (const float*)d_in[1];
    const float* active_variables = (const float*)d_in[2];
    const float* active_functions = (const float*)d_in[3];
    const int* vidx = graph_map;

    float* deg = (float*)d_out;
    char* ws = (char*)d_ws;
    size_t off = 0;
    auto alloc = [&](size_t bytes) -> void* {
        void* p = ws + off; off += (bytes + 255) & ~(size_t)255; return p;
    };
    unsigned long long* gpack = (unsigned long long*)alloc(8ull * Fn);            // 33.6 MB
    unsigned int* packed      = (unsigned int*)alloc(4ull * Vn);                  //  4.0 MB
    unsigned long long* avm   = (unsigned long long*)alloc(8ull * AVW);           //  125 KB
    unsigned long long* svm   = (unsigned long long*)alloc(8ull * AVW);           //  125 KB
    unsigned char* tgrp       = (unsigned char*)alloc(AVW);                       // 15.7 KB
    unsigned short* offs      = (unsigned short*)alloc(2ull * SBLK * OROW);       //  4.2 MB
    unsigned short* offs_T    = (unsigned short*)alloc(2ull * SBLK * OROW);       //  4.2 MB
    unsigned int* sorted4     = (unsigned int*)alloc(4ull * SBLK * RSTRIDE);      // 50.9 MB
    unsigned int* csr         = (unsigned int*)alloc(4ull * 3ull * Fn);           // 50.4 MB
    unsigned int* row_off     = (unsigned int*)alloc(4ull * (Vn + 2));            //  4.0 MB
    unsigned int* bin_total   = (unsigned int*)alloc(4ull * NBP);                 //  4 KB
    unsigned int* bin_base    = (unsigned int*)alloc(4ull * (NBP + 1));           //  4 KB
    unsigned int* cnts        = (unsigned int*)alloc(64);                         // counters
    // aliases onto dead storage:
    unsigned int* tmp       = sorted4;                                   // 4 MB (sorted dead after k_csr)
    unsigned int* frontier0 = (unsigned int*)offs;                       // 4 MB (offs dead after transpose)
    unsigned int* frontier1 = sorted4 + (8u * 1024u * 1024u / 4u);       // 4 MB @ sorted+8MB
    // total ~151.5 MB

    const int BS = 256;
    const int gV = (Vn + BS - 1) / BS;

    k_pack_sort<<<SBLK, 256, 0, stream>>>(vidx, edge_feature, active_functions, gpack, offs, sorted4);
    k_transpose<<<dim3(OROW / 64, SBLK / 64), 256, 0, stream>>>(offs, offs_T);
    k_bin_total<<<(NB + 3) / 4, 256, 0, stream>>>(offs_T, bin_total);
    k_bin_scan<<<1, 1024, 0, stream>>>(bin_total, bin_base, cnts);
    k_csr<<<NB, 1024, 0, stream>>>(offs_T, sorted4, bin_base, active_variables,
                                   csr, row_off, packed, avm, svm, frontier0, cnts + 0);
    k_zero_tmp<<<gV, BS, 0, stream>>>(tmp, tgrp);
    for (int t = 0; t < Tn; ++t) {
        unsigned int* fin  = (t & 1) ? frontier1 : frontier0;
        unsigned int* cin  = cnts + (t & 1);
        unsigned int* fout = (t & 1) ? frontier0 : frontier1;
        unsigned int* cout = cnts + ((t & 1) ^ 1);
        k_fire<<<128, BS, 0, stream>>>(row_off, csr, gpack, fin, cin, cout, tmp, tgrp);
        k_update<<<gV, BS, 0, stream>>>(packed, tmp, avm, svm, tgrp, fout, cout,
                                        deg, (t == Tn - 1) ? 1 : 0);
    }
}